// Round 13
// baseline (890.069 us; speedup 1.0000x reference)
//
#include <hip/hip_runtime.h>

typedef __attribute__((ext_vector_type(8))) short bf16x8;
typedef __attribute__((ext_vector_type(4))) float f32x4;

#define DEV static __device__ __forceinline__

DEV ushort f2bf(float f){
  unsigned u = __float_as_uint(f);
  u += 0x7FFFu + ((u >> 16) & 1u);
  return (ushort)(u >> 16);
}
DEV float bf2f(ushort b){ return __uint_as_float(((unsigned)b) << 16); }

DEV void gload_lds16(const void* g, void* l){
  __builtin_amdgcn_global_load_lds((const __attribute__((address_space(1))) void*)g,
                                   (__attribute__((address_space(3))) void*)l, 16, 0, 0);
}

// extract bf16 halfword e (compile-time) from an int4
DEV unsigned halfword(int4 v, int e){
  unsigned w;
  switch (e >> 1) { case 0: w = (unsigned)v.x; break;
                    case 1: w = (unsigned)v.y; break;
                    case 2: w = (unsigned)v.z; break;
                    default: w = (unsigned)v.w; }
  return (e & 1) ? (w >> 16) : (w & 0xFFFFu);
}

// ---------------- fp32 -> bf16 cast (vectorized, grid-stride) ----------------
__global__ void castk(const float* __restrict__ src, ushort* __restrict__ dst, int n4){
  int stride = gridDim.x * blockDim.x;
  for (int i = blockIdx.x * blockDim.x + threadIdx.x; i < n4; i += stride){
    float4 v = reinterpret_cast<const float4*>(src)[i];
    ushort4 o;
    o.x = f2bf(v.x); o.y = f2bf(v.y); o.z = f2bf(v.z); o.w = f2bf(v.w);
    reinterpret_cast<ushort4*>(dst)[i] = o;
  }
}

// ---------------- bf16 GEMM 256x256 tile, C = A * B^T ----------------
// 8 waves (2M x 4N), BK=32, 4-slot LDS rotation, counted vmcnt(8) pipeline
// (prefetch tile t+3 during tile t; one barrier per K-tile; T1/T3/T4/T5).
template<typename OutT>
__global__ __launch_bounds__(512, 2) void gemm256(const ushort* __restrict__ A,
                                                  const ushort* __restrict__ Bm,
                                                  OutT* __restrict__ C, int M, int N, int K){
  __shared__ alignas(16) ushort As[4*8192];   // 4 slots x [256][32] bf16 = 64KB
  __shared__ alignas(16) ushort Bs[4*8192];   // 4 slots x [256][32] bf16 = 64KB
  const int nTn = N >> 8;
  const int nwg = (M >> 8) * nTn;
  const int cpx = nwg >> 3;                   // nwg divisible by 8 for our shapes
  int bid = blockIdx.x;
  int wg  = (bid & 7) * cpx + (bid >> 3);     // bijective XCD swizzle
  int tm = wg / nTn, tn = wg % nTn;
  int u = threadIdx.x, w = u >> 6, l = u & 63;
  int lr = l & 15, lg = l >> 4;
  int wm = w >> 2, wn = w & 3;                // 2M x 4N wave grid
  const ushort* Abase = A + (size_t)(tm*256)*K;
  const ushort* Bbase = Bm + (size_t)(tn*256)*K;
  const int NT = K >> 5;                      // K-tiles of 32

  f32x4 acc[8][4] = {};

  // ---- stage one K-tile (4 x gload_lds16 per thread; LDS dest linear in lane) ----
  auto stage = [&](int t){
    int s = t & 3;
    #pragma unroll
    for (int l2 = 0; l2 < 2; l2++){
      int c = l2*512 + u;                     // 16B chunk 0..1023 of [256][32]
      int row = c >> 2, kc = (c & 3)*8;
      gload_lds16(Abase + (size_t)row*K + t*32 + kc, &As[s*8192 + c*8]);
    }
    #pragma unroll
    for (int l2 = 0; l2 < 2; l2++){
      int c = l2*512 + u;
      int row = c >> 2, kc = (c & 3)*8;
      gload_lds16(Bbase + (size_t)row*K + t*32 + kc, &Bs[s*8192 + c*8]);
    }
  };

  // ---- prologue: stage tiles 0..2; wait tile 0; join ----
  stage(0); stage(1); stage(2);
  asm volatile("s_waitcnt vmcnt(8)" ::: "memory");
  __builtin_amdgcn_s_barrier();
  __builtin_amdgcn_sched_barrier(0);

  for (int t = 0; t < NT; ++t){
    int st = t & 3;
    const ushort* ApS = &As[st*8192 + (wm*128 + lr)*32 + lg*8];
    const ushort* BpS = &Bs[st*8192 + (wn*64  + lr)*32 + lg*8];

    // B fragments (reused by both phases)
    bf16x8 b0 = *reinterpret_cast<const bf16x8*>(BpS);
    bf16x8 b1 = *reinterpret_cast<const bf16x8*>(BpS + 16*32);
    bf16x8 b2 = *reinterpret_cast<const bf16x8*>(BpS + 32*32);
    bf16x8 b3 = *reinterpret_cast<const bf16x8*>(BpS + 48*32);
    // phase A fragments: mi 0..3
    bf16x8 a0 = *reinterpret_cast<const bf16x8*>(ApS);
    bf16x8 a1 = *reinterpret_cast<const bf16x8*>(ApS + 16*32);
    bf16x8 a2 = *reinterpret_cast<const bf16x8*>(ApS + 32*32);
    bf16x8 a3 = *reinterpret_cast<const bf16x8*>(ApS + 48*32);

    if (t + 3 < NT) stage(t + 3);             // slot (t+3)&3: last read at tile t-1, barrier-separated

    __builtin_amdgcn_s_setprio(1);
    #pragma unroll
    for (int ni = 0; ni < 4; ni++){
      bf16x8 bf = ni==0?b0: ni==1?b1: ni==2?b2: b3;
      acc[0][ni] = __builtin_amdgcn_mfma_f32_16x16x32_bf16(a0, bf, acc[0][ni], 0, 0, 0);
      acc[1][ni] = __builtin_amdgcn_mfma_f32_16x16x32_bf16(a1, bf, acc[1][ni], 0, 0, 0);
      acc[2][ni] = __builtin_amdgcn_mfma_f32_16x16x32_bf16(a2, bf, acc[2][ni], 0, 0, 0);
      acc[3][ni] = __builtin_amdgcn_mfma_f32_16x16x32_bf16(a3, bf, acc[3][ni], 0, 0, 0);
    }
    __builtin_amdgcn_s_setprio(0);

    // phase B fragments: mi 4..7
    bf16x8 a4 = *reinterpret_cast<const bf16x8*>(ApS + 64*32);
    bf16x8 a5 = *reinterpret_cast<const bf16x8*>(ApS + 80*32);
    bf16x8 a6 = *reinterpret_cast<const bf16x8*>(ApS + 96*32);
    bf16x8 a7 = *reinterpret_cast<const bf16x8*>(ApS + 112*32);

    __builtin_amdgcn_s_setprio(1);
    #pragma unroll
    for (int ni = 0; ni < 4; ni++){
      bf16x8 bf = ni==0?b0: ni==1?b1: ni==2?b2: b3;
      acc[4][ni] = __builtin_amdgcn_mfma_f32_16x16x32_bf16(a4, bf, acc[4][ni], 0, 0, 0);
      acc[5][ni] = __builtin_amdgcn_mfma_f32_16x16x32_bf16(a5, bf, acc[5][ni], 0, 0, 0);
      acc[6][ni] = __builtin_amdgcn_mfma_f32_16x16x32_bf16(a6, bf, acc[6][ni], 0, 0, 0);
      acc[7][ni] = __builtin_amdgcn_mfma_f32_16x16x32_bf16(a7, bf, acc[7][ni], 0, 0, 0);
    }
    __builtin_amdgcn_s_setprio(0);

    // boundary: counted drain (tile t+1's loads done; t+2/t+3 stay in flight), then join
    if (t < NT-3)       asm volatile("s_waitcnt vmcnt(8)" ::: "memory");
    else if (t == NT-3) asm volatile("s_waitcnt vmcnt(4)" ::: "memory");
    else if (t == NT-2) asm volatile("s_waitcnt vmcnt(0)" ::: "memory");
    if (t < NT-1){
      __builtin_amdgcn_s_barrier();
      __builtin_amdgcn_sched_barrier(0);
    }
  }

  // ---- epilogue ----
  #pragma unroll
  for (int mi = 0; mi < 8; mi++)
    #pragma unroll
    for (int ni = 0; ni < 4; ni++)
      #pragma unroll
      for (int r = 0; r < 4; r++){
        int row = tm*256 + wm*128 + mi*16 + lg*4 + r;
        int col = tn*256 + wn*64  + ni*16 + lr;
        float v = acc[mi][ni][r];
        if constexpr (sizeof(OutT) == 2) C[(size_t)row*N + col] = (OutT)f2bf(v);
        else                             C[(size_t)row*N + col] = v;
      }
}

// ---------------- RoPE in place on fused QKV buffer ----------------
__global__ __launch_bounds__(256) void rope_kernel(ushort* __restrict__ qkv){
  int bs = blockIdx.x;                  // 0..4095
  int s  = bs & 2047;
  int d  = threadIdx.x & 63, hg = threadIdx.x >> 6;
  float inv = __builtin_amdgcn_exp2f(-(float)d * (13.287712379549449f / 64.0f)); // 10000^(-d/64)
  float ang = (float)s * inv;
  float c = cosf(ang), sn = sinf(ang);
  ushort* row = qkv + (size_t)bs * 6144;
  for (int hh = hg; hh < 40; hh += 4){  // 32 q heads + 8 k heads, contiguous
    ushort* p = row + hh*128;
    float x1 = bf2f(p[d]), x2 = bf2f(p[d+64]);
    p[d]    = f2bf(x1*c - x2*sn);
    p[d+64] = f2bf(x2*c + x1*sn);
  }
}

// ---------------- sliding-window flash attention ----------------
__global__ __launch_bounds__(256) void attn_kernel(const ushort* __restrict__ qkv,
                                                   ushort* __restrict__ ctx){
  constexpr int RS = 6144;
  constexpr int KSb = 272, VTSb = 144, PSb = 144;
  __shared__ alignas(16) char Ks [64*KSb];    // 17408 B
  __shared__ alignas(16) char VTs[128*VTSb];  // 18432 B
  __shared__ alignas(16) char Ps [4*16*PSb];  //  9216 B
  int t = threadIdx.x, w = t >> 6, l = t & 63;
  int lr = l & 15, lg = l >> 4;
  int bid = blockIdx.x;
  int qb = bid & 31, hq = (bid >> 5) & 31, b = bid >> 10;
  int kvh = hq >> 2;
  const ushort* Qb = qkv + (size_t)(b*2048)*RS + hq*128;
  const ushort* Kb = qkv + (size_t)(b*2048)*RS + 4096 + kvh*128;
  const ushort* Vb = qkv + (size_t)(b*2048)*RS + 5120 + kvh*128;
  int i0 = qb*64, i0w = i0 + w*16;
  char* Pw = Ps + w*16*PSb;

  bf16x8 qf[4];
  {
    const ushort* qr = Qb + (size_t)(i0w + lr)*RS + lg*8;
    #pragma unroll
    for (int c = 0; c < 4; c++) qf[c] = *reinterpret_cast<const bf16x8*>(qr + c*32);
  }
  f32x4 acco[8] = {};
  float mrow[4] = {-1e30f,-1e30f,-1e30f,-1e30f};
  float lsum[4] = {0.f,0.f,0.f,0.f};
  const float SCALE = 0.08838834764831845f;   // 1/sqrt(128)
  const float L2E   = 1.4426950408889634f;
  int t0 = qb >= 16 ? qb - 16 : 0;

  for (int tt = t0; tt <= qb; ++tt){
    int j0 = tt*64;
    __syncthreads();
    #pragma unroll
    for (int i = 0; i < 4; i++){
      int c = t + 256*i;
      int row = c >> 4, cole = (c & 15)*8;
      int4 v = *reinterpret_cast<const int4*>(Kb + (size_t)(j0+row)*RS + cole);
      *reinterpret_cast<int4*>(&Ks[row*KSb + cole*2]) = v;
    }
    #pragma unroll
    for (int i = 0; i < 2; i++){
      int u = t + 256*i;
      int cp = u & 15, rp = u >> 4;
      const ushort* vr = Vb + (size_t)(j0 + 2*rp)*RS + cp*8;
      int4 vlo = *reinterpret_cast<const int4*>(vr);
      int4 vhi = *reinterpret_cast<const int4*>(vr + RS);
      #pragma unroll
      for (int e = 0; e < 8; e++){
        unsigned pk = halfword(vlo, e) | (halfword(vhi, e) << 16);
        int dh = cp*8 + e;
        *reinterpret_cast<unsigned*>(&VTs[dh*VTSb + ((rp*4) ^ ((cp & 7) << 4))]) = pk;
      }
    }
    __syncthreads();

    f32x4 accs[4] = {};
    #pragma unroll
    for (int c = 0; c < 4; c++)
      #pragma unroll
      for (int n = 0; n < 4; n++){
        bf16x8 kb = *reinterpret_cast<const bf16x8*>(&Ks[(n*16+lr)*KSb + (c*32+lg*8)*2]);
        accs[n] = __builtin_amdgcn_mfma_f32_16x16x32_bf16(qf[c], kb, accs[n], 0, 0, 0);
      }

    const bool needMask = (tt == qb) || (tt == qb - 16);
    float sc[4][4];
    #pragma unroll
    for (int n = 0; n < 4; n++)
      #pragma unroll
      for (int r = 0; r < 4; r++){
        float v = accs[n][r] * SCALE;
        if (needMask){
          int ii = i0w + lg*4 + r;
          int jj = j0 + n*16 + lr;
          if (jj > ii || ii - jj >= 1024) v = -3e38f;
        }
        sc[n][r] = v;
      }
    float corr[4];
    #pragma unroll
    for (int r = 0; r < 4; r++){
      float tmv = fmaxf(fmaxf(sc[0][r], sc[1][r]), fmaxf(sc[2][r], sc[3][r]));
      #pragma unroll
      for (int d2 = 1; d2 < 16; d2 <<= 1) tmv = fmaxf(tmv, __shfl_xor(tmv, d2));
      float mn = fmaxf(mrow[r], tmv);
      corr[r] = __builtin_amdgcn_exp2f((mrow[r] - mn) * L2E);
      mrow[r] = mn;
    }
    float pv[4][4], ps[4] = {0.f,0.f,0.f,0.f};
    #pragma unroll
    for (int n = 0; n < 4; n++)
      #pragma unroll
      for (int r = 0; r < 4; r++){
        float p = __builtin_amdgcn_exp2f((sc[n][r] - mrow[r]) * L2E);
        pv[n][r] = p; ps[r] += p;
      }
    #pragma unroll
    for (int r = 0; r < 4; r++){
      float s2 = ps[r];
      #pragma unroll
      for (int d2 = 1; d2 < 16; d2 <<= 1) s2 += __shfl_xor(s2, d2);
      lsum[r] = lsum[r]*corr[r] + s2;
    }
    #pragma unroll
    for (int n = 0; n < 8; n++)
      #pragma unroll
      for (int r = 0; r < 4; r++) acco[n][r] *= corr[r];

    #pragma unroll
    for (int n = 0; n < 4; n++)
      #pragma unroll
      for (int r = 0; r < 4; r++)
        *reinterpret_cast<ushort*>(&Pw[(lg*4+r)*PSb + (n*16+lr)*2]) = f2bf(pv[n][r]);
    #pragma unroll
    for (int cc = 0; cc < 2; cc++){
      bf16x8 pa = *reinterpret_cast<const bf16x8*>(&Pw[lr*PSb + (cc*32+lg*8)*2]);
      #pragma unroll
      for (int n = 0; n < 8; n++){
        int dh = n*16 + lr;
        int kvb = (cc*64 + lg*16) ^ (((dh >> 3) & 7) << 4);
        bf16x8 vb = *reinterpret_cast<const bf16x8*>(&VTs[dh*VTSb + kvb]);
        acco[n] = __builtin_amdgcn_mfma_f32_16x16x32_bf16(pa, vb, acco[n], 0, 0, 0);
      }
    }
  }

  float rinv[4];
  #pragma unroll
  for (int r = 0; r < 4; r++) rinv[r] = 1.0f / lsum[r];
  #pragma unroll
  for (int n = 0; n < 8; n++)
    #pragma unroll
    for (int r = 0; r < 4; r++){
      int i = i0w + lg*4 + r;
      ctx[(size_t)(b*2048 + i)*4096 + hq*128 + n*16 + lr] = f2bf(acco[n][r]*rinv[r]);
    }
}

// ---------------- launch ----------------
extern "C" void kernel_launch(void* const* d_in, const int* in_sizes, int n_in,
                              void* d_out, int out_size, void* d_ws, size_t ws_size,
                              hipStream_t stream) {
  const float* hs = (const float*)d_in[0];
  const float* qw = (const float*)d_in[1];
  const float* kw = (const float*)d_in[2];
  const float* vw = (const float*)d_in[3];
  const float* ow = (const float*)d_in[4];
  float* out = (float*)d_out;

  ushort* ws    = (ushort*)d_ws;
  ushort* hs_bf = ws;                       // 16777216 elems
  ushort* wqkv  = ws + 16777216;            // 25165824 elems (q|k|v rows)
  ushort* wo    = wqkv + 25165824;          // 16777216 elems
  ushort* qkvo  = wo + 16777216;            // 25165824 elems
  ushort* ctx   = hs_bf;                    // reuse: hs_bf dead after QKV GEMM

  castk<<<2048, 256, 0, stream>>>(hs, hs_bf, 4194304);
  castk<<<2048, 256, 0, stream>>>(qw, wqkv,            4194304);
  castk<<< 512, 256, 0, stream>>>(kw, wqkv + 16777216, 1048576);
  castk<<< 512, 256, 0, stream>>>(vw, wqkv + 20971520, 1048576);
  castk<<<2048, 256, 0, stream>>>(ow, wo, 4194304);

  gemm256<ushort><<<384, 512, 0, stream>>>(hs_bf, wqkv, qkvo, 4096, 6144, 4096);
  rope_kernel<<<4096, 256, 0, stream>>>(qkvo);
  attn_kernel<<<2048, 256, 0, stream>>>(qkvo, ctx);
  gemm256<float><<<256, 512, 0, stream>>>(ctx, wo, out, 4096, 4096, 4096);
}